// Round 12
// baseline (180.616 us; speedup 1.0000x reference)
//
#include <hip/hip_runtime.h>

#define BLK 256

constexpr int Bn = 4, Cn = 3, Hn = 1024, Wn = 1024;
constexpr int HW   = Hn * Wn;        // 1<<20
constexpr int BHW  = Bn * HW;        // 4,194,304
constexpr int BCHW = Bn * Cn * HW;   // 12,582,912
constexpr int MAX_ITERS = 4;

// dest-tile ownership splat
constexpr int TS  = 64;              // dest tile side
constexpr int Mg  = 24;              // source window margin
constexpr int WND = TS + 2 * Mg;     // 112
constexpr int NPAIR = WND * WND / 2; // 6272 horizontal pixel-pairs
constexpr int PPR = WND / 2;         // 56 pairs per row
constexpr float FMAX = 23.0f;        // = Mg-1; owner handles |f|<=FMAX exactly

constexpr float SCALE = 8192.0f;                 // 2^13
constexpr float INVSC = 1.220703125e-04f;        // 2^-13 exact
constexpr int   BIAS_I = 524288;                 // 2^19

#define STAGEP(PRED, WY, WP, F4, PX, PY)                                      \
    {   PY = ty - Mg + (WY);                                                  \
        PX = tx - Mg + ((WP) << 1);                                           \
        F4 = make_float4(1e9f, 1e9f, 1e9f, 1e9f);                             \
        if ((PRED) && (unsigned)PY < (unsigned)Hn &&                          \
            (unsigned)PX < (unsigned)(Wn - 1))                                \
            F4 = *reinterpret_cast<const float4*>(&flb[(PY << 10) + PX]);     \
    }

// ======================= ABLATION PROBES (R12) =======================
// V1: loop skeleton only. V2: +flow loads+weights. V3: +im0+convert/pack
// (no atomics). Launched BEFORE the real splat_owner, which overwrites
// every acc/wm element -> output unaffected. asm volatile keep-alives
// prevent DCE (guide rule #17).
template<int V>
__global__ __launch_bounds__(1024, 8) void splat_probe(
    const float* __restrict__ im0, const float* __restrict__ flow,
    float* __restrict__ acc, unsigned* __restrict__ wm)
{
    __shared__ unsigned long long s_w1[TS * TS];
    __shared__ unsigned long long s_w2[TS * TS];
    const int bid  = ((blockIdx.x & 7) << 7) | (blockIdx.x >> 3);
    const int b    = bid >> 8;
    const int tile = bid & 255;
    const int ty   = (tile >> 4) * TS;
    const int tx   = (tile & 15) * TS;

    for (int i = threadIdx.x; i < TS * TS; i += 1024) {
        s_w1[i] = 0ull; s_w2[i] = 0ull;
    }
    __syncthreads();

    const float*  imb = im0 + (size_t)b * Cn * HW;
    const float2* flb = reinterpret_cast<const float2*>(flow) + (size_t)b * HW;

    int t  = threadIdx.x;
    int wy = t / PPR, wp = t - wy * PPR;
    int axp, ayp; float4 fA;
    STAGEP(V >= 2, wy, wp, fA, axp, ayp);

    while (t < NPAIR) {
        int nt  = t + 1024;
        int nwp = wp + (1024 % PPR);
        int nwy = wy + (1024 / PPR);
        if (nwp >= PPR) { nwp -= PPR; ++nwy; }
        int bxp, byp; float4 fB;
        STAGEP(V >= 2 && nt < NPAIR, nwy, nwp, fB, bxp, byp);

        if (V == 1) {
            // keep the loop + address math alive; no loads, no body
            asm volatile("" :: "v"(axp), "v"(ayp));
        } else {
#pragma unroll
            for (int k = 0; k < 2; ++k) {
                float fx = k ? fA.z : fA.x;
                float fy = k ? fA.w : fA.y;
                if (!(fabsf(fx) <= FMAX && fabsf(fy) <= FMAX)) continue;
                float X = (float)(axp + k) + fx;
                float Y = (float)ayp + fy;
                float x0 = floorf(X), y0 = floorf(Y);
                int lx0 = (int)x0 - tx;
                int ly0 = (int)y0 - ty;
                if (!(lx0 >= -1 && lx0 < TS && ly0 >= -1 && ly0 < TS)) continue;
                float wxa = 1.f - fabsf(X - x0);
                float wxb = 1.f - fabsf(X - (x0 + 1.f));
                float wya = 1.f - fabsf(Y - y0);
                float wyb = 1.f - fabsf(Y - (y0 + 1.f));
                float w00 = wxa * wya, w01 = wxb * wya;
                float w10 = wxa * wyb, w11 = wxb * wyb;
                bool i00 = (unsigned)ly0     < (unsigned)TS && (unsigned)lx0     < (unsigned)TS && w00 != 0.f;
                bool i01 = (unsigned)ly0     < (unsigned)TS && (unsigned)(lx0+1) < (unsigned)TS && w01 != 0.f;
                bool i10 = (unsigned)(ly0+1) < (unsigned)TS && (unsigned)lx0     < (unsigned)TS && w10 != 0.f;
                bool i11 = (unsigned)(ly0+1) < (unsigned)TS && (unsigned)(lx0+1) < (unsigned)TS && w11 != 0.f;
                if (!(i00 | i01 | i10 | i11)) continue;
                unsigned msk = (unsigned)i00 | ((unsigned)i01 << 1) |
                               ((unsigned)i10 << 2) | ((unsigned)i11 << 3);
                if (V == 2) {
                    asm volatile("" :: "v"(w00), "v"(w01), "v"(w10),
                                      "v"(w11), "v"(msk));
                    continue;
                }
                int p_ = (ayp << 10) + axp + k;
                float sv0 = imb[p_]          * SCALE;
                float sv1 = imb[HW + p_]     * SCALE;
                float sv2 = imb[2 * HW + p_] * SCALE;
#define PCORN(II, C, W)                                                        \
    if (II) {                                                                  \
        int c_ = (C);                                                          \
        unsigned long long a1 =                                                \
            ((unsigned long long)(unsigned)__float2int_rz(sv1 * (W)) << 32) |  \
            (unsigned long long)(unsigned)(__float2int_rz(sv0 * (W)) + BIAS_I);\
        unsigned long long a2 =                                                \
            ((unsigned long long)(unsigned)__float2int_rz(sv2 * (W)) << 32) |  \
            1ull;                                                              \
        asm volatile("" :: "v"((unsigned)a1), "v"((unsigned)(a1 >> 32)),       \
                          "v"((unsigned)(a2 >> 32)), "v"(c_));                 \
    }
                PCORN(i00, ly0 * TS + lx0,           w00)
                PCORN(i01, ly0 * TS + lx0 + 1,       w01)
                PCORN(i10, (ly0 + 1) * TS + lx0,     w10)
                PCORN(i11, (ly0 + 1) * TS + lx0 + 1, w11)
#undef PCORN
            }
        }
        t = nt; wy = nwy; wp = nwp;
        fA = fB; axp = bxp; ayp = byp;
    }
    __syncthreads();

    // identical flush (reads LDS so arrays stay live; real owner overwrites)
    float* accb = acc + (size_t)b * Cn * HW;
    const int lane = threadIdx.x & 63;
    for (int i2 = threadIdx.x; i2 < TS * TS; i2 += 1024) {
        unsigned long long w1 = s_w1[i2], w2 = s_w2[i2];
        unsigned n  = (unsigned)w2;
        int c0 = (int)((unsigned)w1 - (n << 19));
        int c1 = (int)(unsigned)(w1 >> 32);
        int c2 = (int)(unsigned)(w2 >> 32);
        int row = i2 >> 6;
        int p = ((ty + row) << 10) + tx + (i2 & 63);
        accb[p]          = (float)c0 * INVSC;
        accb[HW + p]     = (float)c1 * INVSC;
        accb[2 * HW + p] = (float)c2 * INVSC;
        unsigned long long m = __ballot(n != 0);
        int wbase = (b * HW + ((ty + row) << 10) + tx) >> 5;
        if (lane == 0)  wm[wbase]     = (unsigned)m;
        if (lane == 32) wm[wbase + 1] = (unsigned)(m >> 32);
    }
}
// ===================== end ablation probes =====================

__global__ __launch_bounds__(1024, 8) void splat_owner(
    const float* __restrict__ im0, const float* __restrict__ flow,
    float* __restrict__ acc, unsigned* __restrict__ wm)
{
    __shared__ unsigned long long s_w1[TS * TS];  // [c1 | c0+bias]  32 KiB
    __shared__ unsigned long long s_w2[TS * TS];  // [c2 | count  ]  32 KiB
    const int bid  = ((blockIdx.x & 7) << 7) | (blockIdx.x >> 3);
    const int b    = bid >> 8;
    const int tile = bid & 255;
    const int ty   = (tile >> 4) * TS;
    const int tx   = (tile & 15) * TS;

    for (int i = threadIdx.x; i < TS * TS; i += 1024) {
        s_w1[i] = 0ull; s_w2[i] = 0ull;
    }
    __syncthreads();

    const float*  imb = im0 + (size_t)b * Cn * HW;
    const float2* flb = reinterpret_cast<const float2*>(flow) + (size_t)b * HW;

    int t  = threadIdx.x;
    int wy = t / PPR, wp = t - wy * PPR;
    int axp, ayp; float4 fA;
    STAGEP(true, wy, wp, fA, axp, ayp);

    while (t < NPAIR) {
        int nt  = t + 1024;
        int nwp = wp + (1024 % PPR);
        int nwy = wy + (1024 / PPR);
        if (nwp >= PPR) { nwp -= PPR; ++nwy; }
        int bxp, byp; float4 fB;
        STAGEP(nt < NPAIR, nwy, nwp, fB, bxp, byp);

#pragma unroll
        for (int k = 0; k < 2; ++k) {
            float fx = k ? fA.z : fA.x;
            float fy = k ? fA.w : fA.y;
            if (!(fabsf(fx) <= FMAX && fabsf(fy) <= FMAX)) continue;
            float X = (float)(axp + k) + fx;
            float Y = (float)ayp + fy;
            float x0 = floorf(X), y0 = floorf(Y);
            int lx0 = (int)x0 - tx;
            int ly0 = (int)y0 - ty;
            if (!(lx0 >= -1 && lx0 < TS && ly0 >= -1 && ly0 < TS)) continue;
            float wxa = 1.f - fabsf(X - x0);
            float wxb = 1.f - fabsf(X - (x0 + 1.f));
            float wya = 1.f - fabsf(Y - y0);
            float wyb = 1.f - fabsf(Y - (y0 + 1.f));
            float w00 = wxa * wya, w01 = wxb * wya;
            float w10 = wxa * wyb, w11 = wxb * wyb;
            bool i00 = (unsigned)ly0     < (unsigned)TS && (unsigned)lx0     < (unsigned)TS && w00 != 0.f;
            bool i01 = (unsigned)ly0     < (unsigned)TS && (unsigned)(lx0+1) < (unsigned)TS && w01 != 0.f;
            bool i10 = (unsigned)(ly0+1) < (unsigned)TS && (unsigned)lx0     < (unsigned)TS && w10 != 0.f;
            bool i11 = (unsigned)(ly0+1) < (unsigned)TS && (unsigned)(lx0+1) < (unsigned)TS && w11 != 0.f;
            if (!(i00 | i01 | i10 | i11)) continue;
            int p_ = (ayp << 10) + axp + k;
            float sv0 = imb[p_]          * SCALE;
            float sv1 = imb[HW + p_]     * SCALE;
            float sv2 = imb[2 * HW + p_] * SCALE;
#define CORNER(II, C, W)                                                       \
    if (II) {                                                                  \
        int c_ = (C);                                                          \
        unsigned long long a1 =                                                \
            ((unsigned long long)(unsigned)__float2int_rz(sv1 * (W)) << 32) |  \
            (unsigned long long)(unsigned)(__float2int_rz(sv0 * (W)) + BIAS_I);\
        unsigned long long a2 =                                                \
            ((unsigned long long)(unsigned)__float2int_rz(sv2 * (W)) << 32) |  \
            1ull;                                                              \
        atomicAdd(&s_w1[c_], a1);                                              \
        atomicAdd(&s_w2[c_], a2);                                              \
    }
            CORNER(i00, ly0 * TS + lx0,           w00)
            CORNER(i01, ly0 * TS + lx0 + 1,       w01)
            CORNER(i10, (ly0 + 1) * TS + lx0,     w10)
            CORNER(i11, (ly0 + 1) * TS + lx0 + 1, w11)
#undef CORNER
        }
        t = nt; wy = nwy; wp = nwp;
        fA = fB; axp = bxp; ayp = byp;
    }
    __syncthreads();

    float* accb = acc + (size_t)b * Cn * HW;
    const int lane = threadIdx.x & 63;
    for (int i2 = threadIdx.x; i2 < TS * TS; i2 += 1024) {
        unsigned long long w1 = s_w1[i2], w2 = s_w2[i2];
        unsigned n  = (unsigned)w2;
        int c0 = (int)((unsigned)w1 - (n << 19));
        int c1 = (int)(unsigned)(w1 >> 32);
        int c2 = (int)(unsigned)(w2 >> 32);
        int row = i2 >> 6;
        int p = ((ty + row) << 10) + tx + (i2 & 63);
        accb[p]          = (float)c0 * INVSC;
        accb[HW + p]     = (float)c1 * INVSC;
        accb[2 * HW + p] = (float)c2 * INVSC;
        unsigned long long m = __ballot(n != 0);
        int wbase = (b * HW + ((ty + row) << 10) + tx) >> 5;
        if (lane == 0)  wm[wbase]     = (unsigned)m;
        if (lane == 32) wm[wbase + 1] = (unsigned)(m >> 32);
    }
}

__global__ __launch_bounds__(BLK) void splat_fallback(
    const float* __restrict__ im0, const float* __restrict__ flow,
    float* __restrict__ acc, unsigned* __restrict__ wm)
{
    int t = blockIdx.x * BLK + threadIdx.x;
    if (t >= BHW / 2) return;
    int idx0 = t * 2;
    float4 ff = *reinterpret_cast<const float4*>(&flow[(size_t)idx0 * 2]);

#pragma unroll
    for (int k = 0; k < 2; ++k) {
        float fx = k ? ff.z : ff.x;
        float fy = k ? ff.w : ff.y;
        if (fabsf(fx) <= FMAX && fabsf(fy) <= FMAX) continue;
        int idx = idx0 + k;
        int b = idx >> 20;
        int p = idx & (HW - 1);
        int y = p >> 10;
        int x = p & (Wn - 1);
        float X = (float)x + fx;
        float Y = (float)y + fy;
        float x0 = floorf(X), y0 = floorf(Y);
        float v0 = im0[(b * Cn + 0) * HW + p];
        float v1 = im0[(b * Cn + 1) * HW + p];
        float v2 = im0[(b * Cn + 2) * HW + p];
#pragma unroll
        for (int cy = 0; cy < 2; ++cy) {
#pragma unroll
            for (int cx = 0; cx < 2; ++cx) {
                float xi = x0 + (float)cx;
                float yi = y0 + (float)cy;
                if (xi < 0.f || xi > (float)(Wn - 1) ||
                    yi < 0.f || yi > (float)(Hn - 1)) continue;
                float w = (1.f - fabsf(X - xi)) * (1.f - fabsf(Y - yi));
                if (w == 0.f) continue;
                int di = (int)yi * Wn + (int)xi;
                int gi = b * HW + di;
                atomicOr(&wm[gi >> 5], 1u << (gi & 31));
                atomicAdd(&acc[(b * Cn + 0) * HW + di], v0 * w);
                atomicAdd(&acc[(b * Cn + 1) * HW + di], v1 * w);
                atomicAdd(&acc[(b * Cn + 2) * HW + di], v2 * w);
            }
        }
    }
}

__global__ __launch_bounds__(BLK) void infill_kernel(
    const float* __restrict__ src, const unsigned* __restrict__ wm,
    const float* __restrict__ flowback, float* __restrict__ dst,
    const int* __restrict__ n_iter, int iter)
{
    int n = *n_iter; if (n > MAX_ITERS) n = MAX_ITERS;
    if (iter >= n) return;

    for (int q = blockIdx.x * BLK + threadIdx.x; q < BHW / 4;
         q += gridDim.x * BLK) {
        int idx = q * 4;
        int b = idx >> 20;
        int p = idx & (HW - 1);

        const float* sb = src + (size_t)b * Cn * HW;
        unsigned nib = (wm[idx >> 5] >> (idx & 31)) & 0xFu;
        float4 o0 = *reinterpret_cast<const float4*>(&sb[p]);
        float4 o1 = *reinterpret_cast<const float4*>(&sb[HW + p]);
        float4 o2 = *reinterpret_cast<const float4*>(&sb[2 * HW + p]);

        if (nib != 0xFu) {
            int y = p >> 10, x = p & (Wn - 1);
            const float2* fbp = reinterpret_cast<const float2*>(flowback) + idx;
            float* o0a = reinterpret_cast<float*>(&o0);
            float* o1a = reinterpret_cast<float*>(&o1);
            float* o2a = reinterpret_cast<float*>(&o2);
#pragma unroll
            for (int k = 0; k < 4; ++k) {
                if ((nib >> k) & 1u) continue;
                float2 f = fbp[k];
                float X = (float)(x + k) + f.x;
                float Y = (float)y + f.y;
                float x0 = floorf(X), y0 = floorf(Y);
                float g0 = 0.f, g1 = 0.f, g2 = 0.f;
#pragma unroll
                for (int cy = 0; cy < 2; ++cy) {
#pragma unroll
                    for (int cx = 0; cx < 2; ++cx) {
                        float xi = x0 + (float)cx;
                        float yi = y0 + (float)cy;
                        if (xi < 0.f || xi > (float)(Wn - 1) ||
                            yi < 0.f || yi > (float)(Hn - 1)) continue;
                        float w = (1.f - fabsf(X - xi)) * (1.f - fabsf(Y - yi));
                        int gi = (int)yi * Wn + (int)xi;
                        g0 += sb[gi] * w;
                        g1 += sb[HW + gi] * w;
                        g2 += sb[2 * HW + gi] * w;
                    }
                }
                o0a[k] = g0; o1a[k] = g1; o2a[k] = g2;
            }
        }
        float* db = dst + (size_t)b * Cn * HW;
        *reinterpret_cast<float4*>(&db[p])          = o0;
        *reinterpret_cast<float4*>(&db[HW + p])     = o1;
        *reinterpret_cast<float4*>(&db[2 * HW + p]) = o2;
    }
}

__global__ __launch_bounds__(BLK) void copy_even_kernel(
    const float* __restrict__ A, float* __restrict__ dst,
    const int* __restrict__ n_iter)
{
    int n = *n_iter; if (n > MAX_ITERS) n = MAX_ITERS;
    if (n & 1) return;
    for (int q = blockIdx.x * BLK + threadIdx.x; q < BCHW / 4;
         q += gridDim.x * BLK) {
        int i = q * 4;
        *reinterpret_cast<float4*>(&dst[i]) =
            *reinterpret_cast<const float4*>(&A[i]);
    }
}

extern "C" void kernel_launch(void* const* d_in, const int* in_sizes, int n_in,
                              void* d_out, int out_size, void* d_ws, size_t ws_size,
                              hipStream_t stream)
{
    const float* im0      = (const float*)d_in[0];
    const float* flow     = (const float*)d_in[1];
    const float* flowback = (const float*)d_in[2];
    const int*   n_iter   = (const int*)d_in[3];
    float* out = (float*)d_out;
    float* acc = (float*)d_ws;
    unsigned* wm = (unsigned*)(acc + BCHW);

    // ---- ablation probes (diagnostic round; real owner overwrites) ----
    splat_probe<1><<<Bn * 256, 1024, 0, stream>>>(im0, flow, acc, wm);
    splat_probe<2><<<Bn * 256, 1024, 0, stream>>>(im0, flow, acc, wm);
    splat_probe<3><<<Bn * 256, 1024, 0, stream>>>(im0, flow, acc, wm);

    // ---- real pipeline ----
    splat_owner<<<Bn * 256, 1024, 0, stream>>>(im0, flow, acc, wm);

    splat_fallback<<<(BHW / 2) / BLK, BLK, 0, stream>>>(im0, flow, acc, wm);

    for (int i = 0; i < MAX_ITERS; ++i) {
        const float* s = (i % 2 == 0) ? acc : out;
        float*       d = (i % 2 == 0) ? out : acc;
        int g = (i == 0) ? 4096 : 264;
        infill_kernel<<<g, BLK, 0, stream>>>(s, wm, flowback, d, n_iter, i);
    }

    copy_even_kernel<<<264, BLK, 0, stream>>>(acc, out, n_iter);
}

// Round 13
// 107.281 us; speedup vs baseline: 1.6836x; 1.6836x over previous
//
#include <hip/hip_runtime.h>

#define BLK 256

constexpr int Bn = 4, Cn = 3, Hn = 1024, Wn = 1024;
constexpr int HW   = Hn * Wn;        // 1<<20
constexpr int BHW  = Bn * HW;        // 4,194,304
constexpr int BCHW = Bn * Cn * HW;   // 12,582,912
constexpr int MAX_ITERS = 4;

// dest-tile ownership splat
constexpr int TS  = 64;              // dest tile side
constexpr int Mg  = 24;              // source window margin
constexpr int WND = TS + 2 * Mg;     // 112
constexpr int NPAIR = WND * WND / 2; // 6272 horizontal pixel-pairs
constexpr int PPR = WND / 2;         // 56 pairs per row
constexpr float FMAX = 23.0f;        // = Mg-1; owner handles |f|<=FMAX exactly

// packed-u64 carry-free fixed point:
//   word1: hi = c1*2^13 (mod 2^32 exact), lo = c0*2^13 + 2^19 per event
//   word2: hi = c2*2^13, lo = +1/event (exact count n; n>0 == hole flag)
constexpr float SCALE = 8192.0f;                 // 2^13
constexpr float INVSC = 1.220703125e-04f;        // 2^-13 exact
constexpr int   BIAS_I = 524288;                 // 2^19

#define STAGEP(PRED, WY, WP, F4, PX, PY)                                      \
    {   PY = ty - Mg + (WY);                                                  \
        PX = tx - Mg + ((WP) << 1);                                           \
        F4 = make_float4(1e9f, 1e9f, 1e9f, 1e9f);                             \
        if ((PRED) && (unsigned)PY < (unsigned)Hn &&                          \
            (unsigned)PX < (unsigned)(Wn - 1))                                \
            F4 = *reinterpret_cast<const float4*>(&flb[(PY << 10) + PX]);     \
    }

__global__ __launch_bounds__(1024, 8) void splat_owner(
    const float* __restrict__ im0, const float* __restrict__ flow,
    float* __restrict__ acc, unsigned* __restrict__ wm)
{
    __shared__ unsigned long long s_w1[TS * TS];  // [c1 | c0+bias]  32 KiB
    __shared__ unsigned long long s_w2[TS * TS];  // [c2 | count  ]  32 KiB
    __shared__ unsigned s_nib[1024];              // 4-px hole nibbles (4 KiB)
    const int bid  = ((blockIdx.x & 7) << 7) | (blockIdx.x >> 3);
    const int b    = bid >> 8;
    const int tile = bid & 255;
    const int ty   = (tile >> 4) * TS;
    const int tx   = (tile & 15) * TS;

    for (int i = threadIdx.x; i < TS * TS; i += 1024) {
        s_w1[i] = 0ull; s_w2[i] = 0ull;
    }
    __syncthreads();

    const float*  imb = im0 + (size_t)b * Cn * HW;
    const float2* flb = reinterpret_cast<const float2*>(flow) + (size_t)b * HW;

    int t  = threadIdx.x;
    int wy = t / PPR, wp = t - wy * PPR;
    int axp, ayp; float4 fA;
    STAGEP(true, wy, wp, fA, axp, ayp);

    while (t < NPAIR) {
        int nt  = t + 1024;
        int nwp = wp + (1024 % PPR);
        int nwy = wy + (1024 / PPR);
        if (nwp >= PPR) { nwp -= PPR; ++nwy; }
        int bxp, byp; float4 fB;
        STAGEP(nt < NPAIR, nwy, nwp, fB, bxp, byp);

#pragma unroll
        for (int k = 0; k < 2; ++k) {
            float fx = k ? fA.z : fA.x;
            float fy = k ? fA.w : fA.y;
            if (!(fabsf(fx) <= FMAX && fabsf(fy) <= FMAX)) continue;
            float X = (float)(axp + k) + fx;
            float Y = (float)ayp + fy;
            float x0 = floorf(X), y0 = floorf(Y);
            int lx0 = (int)x0 - tx;
            int ly0 = (int)y0 - ty;
            if (!(lx0 >= -1 && lx0 < TS && ly0 >= -1 && ly0 < TS)) continue;
            float wxa = 1.f - fabsf(X - x0);
            float wxb = 1.f - fabsf(X - (x0 + 1.f));
            float wya = 1.f - fabsf(Y - y0);
            float wyb = 1.f - fabsf(Y - (y0 + 1.f));
            float w00 = wxa * wya, w01 = wxb * wya;
            float w10 = wxa * wyb, w11 = wxb * wyb;
            bool i00 = (unsigned)ly0     < (unsigned)TS && (unsigned)lx0     < (unsigned)TS && w00 != 0.f;
            bool i01 = (unsigned)ly0     < (unsigned)TS && (unsigned)(lx0+1) < (unsigned)TS && w01 != 0.f;
            bool i10 = (unsigned)(ly0+1) < (unsigned)TS && (unsigned)lx0     < (unsigned)TS && w10 != 0.f;
            bool i11 = (unsigned)(ly0+1) < (unsigned)TS && (unsigned)(lx0+1) < (unsigned)TS && w11 != 0.f;
            if (!(i00 | i01 | i10 | i11)) continue;
            int p_ = (ayp << 10) + axp + k;
            float sv0 = imb[p_]          * SCALE;
            float sv1 = imb[HW + p_]     * SCALE;
            float sv2 = imb[2 * HW + p_] * SCALE;
#define CORNER(II, C, W)                                                       \
    if (II) {                                                                  \
        int c_ = (C);                                                          \
        unsigned long long a1 =                                                \
            ((unsigned long long)(unsigned)__float2int_rz(sv1 * (W)) << 32) |  \
            (unsigned long long)(unsigned)(__float2int_rz(sv0 * (W)) + BIAS_I);\
        unsigned long long a2 =                                                \
            ((unsigned long long)(unsigned)__float2int_rz(sv2 * (W)) << 32) |  \
            1ull;                                                              \
        atomicAdd(&s_w1[c_], a1);                                              \
        atomicAdd(&s_w2[c_], a2);                                              \
    }
            CORNER(i00, ly0 * TS + lx0,           w00)
            CORNER(i01, ly0 * TS + lx0 + 1,       w01)
            CORNER(i10, (ly0 + 1) * TS + lx0,     w10)
            CORNER(i11, (ly0 + 1) * TS + lx0 + 1, w11)
#undef CORNER
        }
        t = nt; wy = nwy; wp = nwp;
        fA = fB; axp = bxp; ayp = byp;
    }
    __syncthreads();

    // -------- vectorized flush (R12 ablation: 4B scalar stores were the
    // 50us floor -- 50MB at ~1TB/s). Each thread converts 4 consecutive px
    // and issues 3x global_store_dwordx4 (16B/lane). --------
    float* accb = acc + (size_t)b * Cn * HW;
    {
        const int t4 = threadIdx.x;           // owns px 4*t4 .. 4*t4+3
        float4 o0, o1, o2;
        unsigned nib = 0;
#pragma unroll
        for (int j = 0; j < 4; ++j) {
            int i2 = t4 * 4 + j;
            unsigned long long w1 = s_w1[i2], w2 = s_w2[i2];
            unsigned n = (unsigned)w2;
            reinterpret_cast<float*>(&o0)[j] =
                (float)(int)((unsigned)w1 - (n << 19)) * INVSC;
            reinterpret_cast<float*>(&o1)[j] =
                (float)(int)(unsigned)(w1 >> 32) * INVSC;
            reinterpret_cast<float*>(&o2)[j] =
                (float)(int)(unsigned)(w2 >> 32) * INVSC;
            nib |= (n != 0 ? 1u : 0u) << j;
        }
        int row = t4 >> 4;                    // (4*t4)>>6
        int col = (t4 & 15) << 2;             // (4*t4)&63
        int p = ((ty + row) << 10) + tx + col;
        *reinterpret_cast<float4*>(&accb[p])          = o0;
        *reinterpret_cast<float4*>(&accb[HW + p])     = o1;
        *reinterpret_cast<float4*>(&accb[2 * HW + p]) = o2;
        s_nib[t4] = nib;
    }
    __syncthreads();
    // assemble 128 wm words (32 px each) from nibbles
    if (threadIdx.x < 128) {
        int t2  = threadIdx.x;
        int row = t2 >> 1, seg = t2 & 1;
        unsigned wword = 0;
#pragma unroll
        for (int q = 0; q < 8; ++q)
            wword |= s_nib[row * 16 + seg * 8 + q] << (4 * q);
        wm[((b * HW + ((ty + row) << 10) + tx) >> 5) + seg] = wword;
    }
}

// ------- fallback: the rare |flow|>FMAX pixels, scattered atomics -------
__global__ __launch_bounds__(BLK) void splat_fallback(
    const float* __restrict__ im0, const float* __restrict__ flow,
    float* __restrict__ acc, unsigned* __restrict__ wm)
{
    int t = blockIdx.x * BLK + threadIdx.x;
    if (t >= BHW / 2) return;
    int idx0 = t * 2;
    float4 ff = *reinterpret_cast<const float4*>(&flow[(size_t)idx0 * 2]);

#pragma unroll
    for (int k = 0; k < 2; ++k) {
        float fx = k ? ff.z : ff.x;
        float fy = k ? ff.w : ff.y;
        if (fabsf(fx) <= FMAX && fabsf(fy) <= FMAX) continue;
        int idx = idx0 + k;
        int b = idx >> 20;
        int p = idx & (HW - 1);
        int y = p >> 10;
        int x = p & (Wn - 1);
        float X = (float)x + fx;
        float Y = (float)y + fy;
        float x0 = floorf(X), y0 = floorf(Y);
        float v0 = im0[(b * Cn + 0) * HW + p];
        float v1 = im0[(b * Cn + 1) * HW + p];
        float v2 = im0[(b * Cn + 2) * HW + p];
#pragma unroll
        for (int cy = 0; cy < 2; ++cy) {
#pragma unroll
            for (int cx = 0; cx < 2; ++cx) {
                float xi = x0 + (float)cx;
                float yi = y0 + (float)cy;
                if (xi < 0.f || xi > (float)(Wn - 1) ||
                    yi < 0.f || yi > (float)(Hn - 1)) continue;
                float w = (1.f - fabsf(X - xi)) * (1.f - fabsf(Y - yi));
                if (w == 0.f) continue;
                int di = (int)yi * Wn + (int)xi;
                int gi = b * HW + di;
                atomicOr(&wm[gi >> 5], 1u << (gi & 31));
                atomicAdd(&acc[(b * Cn + 0) * HW + di], v0 * w);
                atomicAdd(&acc[(b * Cn + 1) * HW + di], v1 * w);
                atomicAdd(&acc[(b * Cn + 2) * HW + di], v2 * w);
            }
        }
    }
}

// ------- infill iteration: dst = where(hole, gather(src,flowback), src) -----
__global__ __launch_bounds__(BLK) void infill_kernel(
    const float* __restrict__ src, const unsigned* __restrict__ wm,
    const float* __restrict__ flowback, float* __restrict__ dst,
    const int* __restrict__ n_iter, int iter)
{
    int n = *n_iter; if (n > MAX_ITERS) n = MAX_ITERS;
    if (iter >= n) return;

    for (int q = blockIdx.x * BLK + threadIdx.x; q < BHW / 4;
         q += gridDim.x * BLK) {
        int idx = q * 4;
        int b = idx >> 20;
        int p = idx & (HW - 1);

        const float* sb = src + (size_t)b * Cn * HW;
        unsigned nib = (wm[idx >> 5] >> (idx & 31)) & 0xFu;
        float4 o0 = *reinterpret_cast<const float4*>(&sb[p]);
        float4 o1 = *reinterpret_cast<const float4*>(&sb[HW + p]);
        float4 o2 = *reinterpret_cast<const float4*>(&sb[2 * HW + p]);

        if (nib != 0xFu) {
            int y = p >> 10, x = p & (Wn - 1);
            const float2* fbp = reinterpret_cast<const float2*>(flowback) + idx;
            float* o0a = reinterpret_cast<float*>(&o0);
            float* o1a = reinterpret_cast<float*>(&o1);
            float* o2a = reinterpret_cast<float*>(&o2);
#pragma unroll
            for (int k = 0; k < 4; ++k) {
                if ((nib >> k) & 1u) continue;
                float2 f = fbp[k];
                float X = (float)(x + k) + f.x;
                float Y = (float)y + f.y;
                float x0 = floorf(X), y0 = floorf(Y);
                float g0 = 0.f, g1 = 0.f, g2 = 0.f;
#pragma unroll
                for (int cy = 0; cy < 2; ++cy) {
#pragma unroll
                    for (int cx = 0; cx < 2; ++cx) {
                        float xi = x0 + (float)cx;
                        float yi = y0 + (float)cy;
                        if (xi < 0.f || xi > (float)(Wn - 1) ||
                            yi < 0.f || yi > (float)(Hn - 1)) continue;
                        float w = (1.f - fabsf(X - xi)) * (1.f - fabsf(Y - yi));
                        int gi = (int)yi * Wn + (int)xi;
                        g0 += sb[gi] * w;
                        g1 += sb[HW + gi] * w;
                        g2 += sb[2 * HW + gi] * w;
                    }
                }
                o0a[k] = g0; o1a[k] = g1; o2a[k] = g2;
            }
        }
        float* db = dst + (size_t)b * Cn * HW;
        *reinterpret_cast<float4*>(&db[p])          = o0;
        *reinterpret_cast<float4*>(&db[HW + p])     = o1;
        *reinterpret_cast<float4*>(&db[2 * HW + p]) = o2;
    }
}

__global__ __launch_bounds__(BLK) void copy_even_kernel(
    const float* __restrict__ A, float* __restrict__ dst,
    const int* __restrict__ n_iter)
{
    int n = *n_iter; if (n > MAX_ITERS) n = MAX_ITERS;
    if (n & 1) return;
    for (int q = blockIdx.x * BLK + threadIdx.x; q < BCHW / 4;
         q += gridDim.x * BLK) {
        int i = q * 4;
        *reinterpret_cast<float4*>(&dst[i]) =
            *reinterpret_cast<const float4*>(&A[i]);
    }
}

extern "C" void kernel_launch(void* const* d_in, const int* in_sizes, int n_in,
                              void* d_out, int out_size, void* d_ws, size_t ws_size,
                              hipStream_t stream)
{
    const float* im0      = (const float*)d_in[0];
    const float* flow     = (const float*)d_in[1];
    const float* flowback = (const float*)d_in[2];
    const int*   n_iter   = (const int*)d_in[3];
    float* out = (float*)d_out;
    float* acc = (float*)d_ws;
    unsigned* wm = (unsigned*)(acc + BCHW);

    splat_owner<<<Bn * 256, 1024, 0, stream>>>(im0, flow, acc, wm);

    splat_fallback<<<(BHW / 2) / BLK, BLK, 0, stream>>>(im0, flow, acc, wm);

    for (int i = 0; i < MAX_ITERS; ++i) {
        const float* s = (i % 2 == 0) ? acc : out;
        float*       d = (i % 2 == 0) ? out : acc;
        int g = (i == 0) ? 4096 : 264;
        infill_kernel<<<g, BLK, 0, stream>>>(s, wm, flowback, d, n_iter, i);
    }

    copy_even_kernel<<<264, BLK, 0, stream>>>(acc, out, n_iter);
}

// Round 14
// 106.293 us; speedup vs baseline: 1.6992x; 1.0093x over previous
//
#include <hip/hip_runtime.h>

#define BLK 256

constexpr int Bn = 4, Cn = 3, Hn = 1024, Wn = 1024;
constexpr int HW   = Hn * Wn;        // 1<<20
constexpr int BHW  = Bn * HW;        // 4,194,304
constexpr int BCHW = Bn * Cn * HW;   // 12,582,912
constexpr int MAX_ITERS = 4;

constexpr int TS  = 64;              // dest tile side
constexpr int Mg  = 24;              // source window margin
constexpr int WND = TS + 2 * Mg;     // 112
constexpr int NPAIR = WND * WND / 2; // 6272 horizontal pixel-pairs
constexpr int PPR = WND / 2;         // 56 pairs per row
constexpr float FMAX = 23.0f;        // = Mg-1; owner handles |f|<=FMAX exactly

constexpr float SCALE = 8192.0f;                 // 2^13
constexpr float INVSC = 1.220703125e-04f;        // 2^-13 exact
constexpr int   BIAS_I = 524288;                 // 2^19

// tile-major acc layout (R13 post-mortem: standard-layout flush = 256B
// segments @4KB stride from 512 concurrent blocks -> ~1 TB/s HBM write
// commit was the invariant 50us floor; linear per-block flush fixes it):
//   accT[((b*256 + tile)*3 + c)*4096 + (y&63)*64 + (x&63)], tile=(y>>6)*16+(x>>6)
__device__ __forceinline__ size_t tile_base(int b, int y, int x) {
    int tile = ((y >> 6) << 4) | (x >> 6);
    return ((size_t)(b * 256 + tile) * 3) << 12;
}
__device__ __forceinline__ int tile_within(int y, int x) {
    return ((y & 63) << 6) | (x & 63);
}

#define STAGEP(PRED, WY, WP, F4, PX, PY)                                      \
    {   PY = ty - Mg + (WY);                                                  \
        PX = tx - Mg + ((WP) << 1);                                           \
        F4 = make_float4(1e9f, 1e9f, 1e9f, 1e9f);                             \
        if ((PRED) && (unsigned)PY < (unsigned)Hn &&                          \
            (unsigned)PX < (unsigned)(Wn - 1))                                \
            F4 = *reinterpret_cast<const float4*>(&flb[(PY << 10) + PX]);     \
    }

__global__ __launch_bounds__(1024, 8) void splat_owner(
    const float* __restrict__ im0, const float* __restrict__ flow,
    float* __restrict__ acc, unsigned* __restrict__ wm)
{
    __shared__ unsigned long long s_w1[TS * TS];  // [c1 | c0+bias]  32 KiB
    __shared__ unsigned long long s_w2[TS * TS];  // [c2 | count  ]  32 KiB
    __shared__ unsigned s_nib[1024];              // 4-px hole nibbles (4 KiB)
    const int bid  = ((blockIdx.x & 7) << 7) | (blockIdx.x >> 3);
    const int b    = bid >> 8;
    const int tile = bid & 255;
    const int ty   = (tile >> 4) * TS;
    const int tx   = (tile & 15) * TS;

    for (int i = threadIdx.x; i < TS * TS; i += 1024) {
        s_w1[i] = 0ull; s_w2[i] = 0ull;
    }
    __syncthreads();

    const float*  imb = im0 + (size_t)b * Cn * HW;
    const float2* flb = reinterpret_cast<const float2*>(flow) + (size_t)b * HW;

    int t  = threadIdx.x;
    int wy = t / PPR, wp = t - wy * PPR;
    int axp, ayp; float4 fA;
    STAGEP(true, wy, wp, fA, axp, ayp);

    while (t < NPAIR) {
        int nt  = t + 1024;
        int nwp = wp + (1024 % PPR);
        int nwy = wy + (1024 / PPR);
        if (nwp >= PPR) { nwp -= PPR; ++nwy; }
        int bxp, byp; float4 fB;
        STAGEP(nt < NPAIR, nwy, nwp, fB, bxp, byp);

#pragma unroll
        for (int k = 0; k < 2; ++k) {
            float fx = k ? fA.z : fA.x;
            float fy = k ? fA.w : fA.y;
            if (!(fabsf(fx) <= FMAX && fabsf(fy) <= FMAX)) continue;
            float X = (float)(axp + k) + fx;
            float Y = (float)ayp + fy;
            float x0 = floorf(X), y0 = floorf(Y);
            int lx0 = (int)x0 - tx;
            int ly0 = (int)y0 - ty;
            if (!(lx0 >= -1 && lx0 < TS && ly0 >= -1 && ly0 < TS)) continue;
            float wxa = 1.f - fabsf(X - x0);
            float wxb = 1.f - fabsf(X - (x0 + 1.f));
            float wya = 1.f - fabsf(Y - y0);
            float wyb = 1.f - fabsf(Y - (y0 + 1.f));
            float w00 = wxa * wya, w01 = wxb * wya;
            float w10 = wxa * wyb, w11 = wxb * wyb;
            bool i00 = (unsigned)ly0     < (unsigned)TS && (unsigned)lx0     < (unsigned)TS && w00 != 0.f;
            bool i01 = (unsigned)ly0     < (unsigned)TS && (unsigned)(lx0+1) < (unsigned)TS && w01 != 0.f;
            bool i10 = (unsigned)(ly0+1) < (unsigned)TS && (unsigned)lx0     < (unsigned)TS && w10 != 0.f;
            bool i11 = (unsigned)(ly0+1) < (unsigned)TS && (unsigned)(lx0+1) < (unsigned)TS && w11 != 0.f;
            if (!(i00 | i01 | i10 | i11)) continue;
            int p_ = (ayp << 10) + axp + k;
            float sv0 = imb[p_]          * SCALE;
            float sv1 = imb[HW + p_]     * SCALE;
            float sv2 = imb[2 * HW + p_] * SCALE;
#define CORNER(II, C, W)                                                       \
    if (II) {                                                                  \
        int c_ = (C);                                                          \
        unsigned long long a1 =                                                \
            ((unsigned long long)(unsigned)__float2int_rz(sv1 * (W)) << 32) |  \
            (unsigned long long)(unsigned)(__float2int_rz(sv0 * (W)) + BIAS_I);\
        unsigned long long a2 =                                                \
            ((unsigned long long)(unsigned)__float2int_rz(sv2 * (W)) << 32) |  \
            1ull;                                                              \
        atomicAdd(&s_w1[c_], a1);                                              \
        atomicAdd(&s_w2[c_], a2);                                              \
    }
            CORNER(i00, ly0 * TS + lx0,           w00)
            CORNER(i01, ly0 * TS + lx0 + 1,       w01)
            CORNER(i10, (ly0 + 1) * TS + lx0,     w10)
            CORNER(i11, (ly0 + 1) * TS + lx0 + 1, w11)
#undef CORNER
        }
        t = nt; wy = nwy; wp = nwp;
        fA = fB; axp = bxp; ayp = byp;
    }
    __syncthreads();

    // -------- LINEAR flush into tile-major acc (48 KiB contiguous/block) ----
    float* outp = acc + (((size_t)(b * 256 + tile) * 3) << 12);
    {
        const int t4 = threadIdx.x;           // owns within-px 4*t4..4*t4+3
        float4 o0, o1, o2;
        unsigned nib = 0;
#pragma unroll
        for (int j = 0; j < 4; ++j) {
            int i2 = t4 * 4 + j;
            unsigned long long w1 = s_w1[i2], w2 = s_w2[i2];
            unsigned n = (unsigned)w2;
            reinterpret_cast<float*>(&o0)[j] =
                (float)(int)((unsigned)w1 - (n << 19)) * INVSC;
            reinterpret_cast<float*>(&o1)[j] =
                (float)(int)(unsigned)(w1 >> 32) * INVSC;
            reinterpret_cast<float*>(&o2)[j] =
                (float)(int)(unsigned)(w2 >> 32) * INVSC;
            nib |= (n != 0 ? 1u : 0u) << j;
        }
        *reinterpret_cast<float4*>(&outp[t4 * 4])        = o0;
        *reinterpret_cast<float4*>(&outp[4096 + t4 * 4]) = o1;
        *reinterpret_cast<float4*>(&outp[8192 + t4 * 4]) = o2;
        s_nib[t4] = nib;
    }
    __syncthreads();
    if (threadIdx.x < 128) {
        int t2  = threadIdx.x;
        int row = t2 >> 1, seg = t2 & 1;
        unsigned wword = 0;
#pragma unroll
        for (int q = 0; q < 8; ++q)
            wword |= s_nib[row * 16 + seg * 8 + q] << (4 * q);
        wm[((b * HW + ((ty + row) << 10) + tx) >> 5) + seg] = wword;
    }
}

// ------- fallback: rare |flow|>FMAX pixels, scattered atomics (tiled acc) ---
__global__ __launch_bounds__(BLK) void splat_fallback(
    const float* __restrict__ im0, const float* __restrict__ flow,
    float* __restrict__ acc, unsigned* __restrict__ wm)
{
    int t = blockIdx.x * BLK + threadIdx.x;
    if (t >= BHW / 2) return;
    int idx0 = t * 2;
    float4 ff = *reinterpret_cast<const float4*>(&flow[(size_t)idx0 * 2]);

#pragma unroll
    for (int k = 0; k < 2; ++k) {
        float fx = k ? ff.z : ff.x;
        float fy = k ? ff.w : ff.y;
        if (fabsf(fx) <= FMAX && fabsf(fy) <= FMAX) continue;
        int idx = idx0 + k;
        int b = idx >> 20;
        int p = idx & (HW - 1);
        int y = p >> 10;
        int x = p & (Wn - 1);
        float X = (float)x + fx;
        float Y = (float)y + fy;
        float x0 = floorf(X), y0 = floorf(Y);
        float v0 = im0[(b * Cn + 0) * HW + p];
        float v1 = im0[(b * Cn + 1) * HW + p];
        float v2 = im0[(b * Cn + 2) * HW + p];
#pragma unroll
        for (int cy = 0; cy < 2; ++cy) {
#pragma unroll
            for (int cx = 0; cx < 2; ++cx) {
                float xi = x0 + (float)cx;
                float yi = y0 + (float)cy;
                if (xi < 0.f || xi > (float)(Wn - 1) ||
                    yi < 0.f || yi > (float)(Hn - 1)) continue;
                float w = (1.f - fabsf(X - xi)) * (1.f - fabsf(Y - yi));
                if (w == 0.f) continue;
                int dy = (int)yi, dx = (int)xi;
                int gi = b * HW + dy * Wn + dx;
                atomicOr(&wm[gi >> 5], 1u << (gi & 31));
                size_t tb = tile_base(b, dy, dx);
                int    wi = tile_within(dy, dx);
                atomicAdd(&acc[tb + wi],        v0 * w);
                atomicAdd(&acc[tb + 4096 + wi], v1 * w);
                atomicAdd(&acc[tb + 8192 + wi], v2 * w);
            }
        }
    }
}

// ------- infill: dst = where(hole, gather(src,flowback), src) ---------------
// TILED=1: src is tile-major (iter 0). TILED=0: standard layout (iters >=1).
// dst always standard. 4 px/thread float4, grid-stride.
template<int TILED>
__global__ __launch_bounds__(BLK) void infill_kernel(
    const float* __restrict__ src, const unsigned* __restrict__ wm,
    const float* __restrict__ flowback, float* __restrict__ dst,
    const int* __restrict__ n_iter, int iter)
{
    int n = *n_iter; if (n > MAX_ITERS) n = MAX_ITERS;
    if (iter >= n) return;

    for (int q = blockIdx.x * BLK + threadIdx.x; q < BHW / 4;
         q += gridDim.x * BLK) {
        int idx = q * 4;
        int b = idx >> 20;
        int p = idx & (HW - 1);
        int y = p >> 10, x = p & (Wn - 1);

        const float* sb = src + (size_t)b * Cn * HW;   // standard-layout base
        unsigned nib = (wm[idx >> 5] >> (idx & 31)) & 0xFu;
        float4 o0, o1, o2;
        if (TILED) {
            size_t tb = tile_base(b, y, x);
            int    wi = tile_within(y, x);             // x%4==0 -> intra-tile
            o0 = *reinterpret_cast<const float4*>(&src[tb + wi]);
            o1 = *reinterpret_cast<const float4*>(&src[tb + 4096 + wi]);
            o2 = *reinterpret_cast<const float4*>(&src[tb + 8192 + wi]);
        } else {
            o0 = *reinterpret_cast<const float4*>(&sb[p]);
            o1 = *reinterpret_cast<const float4*>(&sb[HW + p]);
            o2 = *reinterpret_cast<const float4*>(&sb[2 * HW + p]);
        }

        if (nib != 0xFu) {
            const float2* fbp = reinterpret_cast<const float2*>(flowback) + idx;
            float* o0a = reinterpret_cast<float*>(&o0);
            float* o1a = reinterpret_cast<float*>(&o1);
            float* o2a = reinterpret_cast<float*>(&o2);
#pragma unroll
            for (int k = 0; k < 4; ++k) {
                if ((nib >> k) & 1u) continue;
                float2 f = fbp[k];
                float X = (float)(x + k) + f.x;
                float Y = (float)y + f.y;
                float x0 = floorf(X), y0 = floorf(Y);
                float g0 = 0.f, g1 = 0.f, g2 = 0.f;
#pragma unroll
                for (int cy = 0; cy < 2; ++cy) {
#pragma unroll
                    for (int cx = 0; cx < 2; ++cx) {
                        float xi = x0 + (float)cx;
                        float yi = y0 + (float)cy;
                        if (xi < 0.f || xi > (float)(Wn - 1) ||
                            yi < 0.f || yi > (float)(Hn - 1)) continue;
                        float w = (1.f - fabsf(X - xi)) * (1.f - fabsf(Y - yi));
                        int gy = (int)yi, gx = (int)xi;
                        if (TILED) {
                            size_t tb2 = tile_base(b, gy, gx);
                            int    wi2 = tile_within(gy, gx);
                            g0 += src[tb2 + wi2]        * w;
                            g1 += src[tb2 + 4096 + wi2] * w;
                            g2 += src[tb2 + 8192 + wi2] * w;
                        } else {
                            int gi = gy * Wn + gx;
                            g0 += sb[gi] * w;
                            g1 += sb[HW + gi] * w;
                            g2 += sb[2 * HW + gi] * w;
                        }
                    }
                }
                o0a[k] = g0; o1a[k] = g1; o2a[k] = g2;
            }
        }
        float* db = dst + (size_t)b * Cn * HW;
        *reinterpret_cast<float4*>(&db[p])          = o0;
        *reinterpret_cast<float4*>(&db[HW + p])     = o1;
        *reinterpret_cast<float4*>(&db[2 * HW + p]) = o2;
    }
}

// ------- n even: result is in acc. n==0 -> acc is tile-major (de-tile);
// n>=2 -> acc holds standard layout (written by infill iter n-1). -----------
__global__ __launch_bounds__(BLK) void copy_even_kernel(
    const float* __restrict__ A, float* __restrict__ dst,
    const int* __restrict__ n_iter)
{
    int n = *n_iter; if (n > MAX_ITERS) n = MAX_ITERS;
    if (n & 1) return;
    bool tiled = (n == 0);
    for (int q = blockIdx.x * BLK + threadIdx.x; q < BCHW / 4;
         q += gridDim.x * BLK) {
        int idx = q * 4;
        float4 v;
        if (tiled) {
            int bc = idx >> 20;
            int b = bc / 3, c = bc - 3 * b;
            int p = idx & (HW - 1);
            int y = p >> 10, x = p & (Wn - 1);
            v = *reinterpret_cast<const float4*>(
                &A[tile_base(b, y, x) + (size_t)c * 4096 + tile_within(y, x)]);
        } else {
            v = *reinterpret_cast<const float4*>(&A[idx]);
        }
        *reinterpret_cast<float4*>(&dst[idx]) = v;
    }
}

extern "C" void kernel_launch(void* const* d_in, const int* in_sizes, int n_in,
                              void* d_out, int out_size, void* d_ws, size_t ws_size,
                              hipStream_t stream)
{
    const float* im0      = (const float*)d_in[0];
    const float* flow     = (const float*)d_in[1];
    const float* flowback = (const float*)d_in[2];
    const int*   n_iter   = (const int*)d_in[3];
    float* out = (float*)d_out;
    float* acc = (float*)d_ws;                       // BCHW floats, tile-major
    unsigned* wm = (unsigned*)(acc + BCHW);          // BHW/32 mask words

    splat_owner<<<Bn * 256, 1024, 0, stream>>>(im0, flow, acc, wm);

    splat_fallback<<<(BHW / 2) / BLK, BLK, 0, stream>>>(im0, flow, acc, wm);

    // iter 0: tiled acc -> out; iters >=1 (gated no-ops for n==1) standard.
    infill_kernel<1><<<4096, BLK, 0, stream>>>(acc, wm, flowback, out, n_iter, 0);
    for (int i = 1; i < MAX_ITERS; ++i) {
        const float* s = (i % 2 == 0) ? acc : out;
        float*       d = (i % 2 == 0) ? out : acc;
        infill_kernel<0><<<264, BLK, 0, stream>>>(s, wm, flowback, d, n_iter, i);
    }

    copy_even_kernel<<<264, BLK, 0, stream>>>(acc, out, n_iter);
}